// Round 2
// baseline (849.505 us; speedup 1.0000x reference)
//
#include <hip/hip_runtime.h>
#include <cmath>

// ---------------------------------------------------------------------------
// UPGAT forward — "gathered rows only" restructure.
//
// Key algebra: output only needs ent_new at triple head/tail slots (NS = 2B =
// 8192 of N=100000) and the scatter-aggregate commutes with @W1^T:
//   h_num[n] = (ab*(e0[n].g0) + sum_e a_e*(e0[dst].g_rel)) @ W1^T
// so the per-edge c matrix is never materialized; the edge GEMM exists only
// to produce scores (epilogue: tanh . e0[src] . Wa partial dot -> atomicAdd).
//
// Pipeline (all on `stream`):
//   1. inv_norm[n] = 1/max(||ent_emb[n]||,eps)         [N]      (e0 = emb*inv)
//   2. global CSR over src (hist/scan/bucket)           O(E)
//   3. slotNode[r] (r<NS: triple head/tail), deg[r], slot_off scan,
//      rows[m] = edge ids grouped per slot (M ~ 12K)
//   4. edge GEMM  (rows x 512 @ W1^T), EPI=score scatter -> score_e[M]
//   5. slot GEMM  (NS x 512 @ W1^T),  EPI=score scatter -> score_s[NS]
//   6. exp(-leaky) on both score arrays
//   7. P[r] = ab*(e0.g0) + sum a_e*(e0[dst].g_rel); inv_denom[r]  (CSR, no atomics)
//   8. hp GEMM:  H = elu((P @ W1^T) * inv_denom)
//   9. ent GEMM: ENT = e0[slot] @ WE + H; l2norm rows in place
//  10. rel GEMM: relnew = rel_emb @ WR
//  11. gather -> out [B,3,512]
// Workspace: ~54 MB.
// ---------------------------------------------------------------------------

#define DDIM 512
#define TILE 64
#define KT   16
#define LDSP 68
#define MAXM 65536   // bound on total selected edge-rows (expected ~12K)

__device__ __forceinline__ float elu1(float x) { return x > 0.f ? x : expm1f(x); }

// ---- inverse L2 norm per row ----------------------------------------------
__global__ __launch_bounds__(128)
void invnorm_kernel(const float* __restrict__ emb, float* __restrict__ invN)
{
    int r = blockIdx.x, t = threadIdx.x;
    float4 v = *(const float4*)(emb + (size_t)r * DDIM + t * 4);
    float s = v.x*v.x + v.y*v.y + v.z*v.z + v.w*v.w;
    #pragma unroll
    for (int off = 32; off > 0; off >>= 1) s += __shfl_down(s, off);
    __shared__ float ws[2];
    if ((t & 63) == 0) ws[t >> 6] = s;
    __syncthreads();
    if (t == 0) invN[r] = 1.f / fmaxf(sqrtf(ws[0] + ws[1]), 1e-12f);
}

// ---- row-wise L2 normalize in place ---------------------------------------
__global__ __launch_bounds__(128)
void l2norm_kernel(float* __restrict__ data)
{
    int r = blockIdx.x, t = threadIdx.x;
    size_t o = (size_t)r * DDIM + t * 4;
    float4 v = *(const float4*)(data + o);
    float s = v.x*v.x + v.y*v.y + v.z*v.z + v.w*v.w;
    #pragma unroll
    for (int off = 32; off > 0; off >>= 1) s += __shfl_down(s, off);
    __shared__ float ws[2];
    if ((t & 63) == 0) ws[t >> 6] = s;
    __syncthreads();
    float inv = 1.f / fmaxf(sqrtf(ws[0] + ws[1]), 1e-12f);
    *(float4*)(data + o) = make_float4(v.x*inv, v.y*inv, v.z*inv, v.w*inv);
}

// ---- CSR build over src ----------------------------------------------------
__global__ void hist_kernel(const int* __restrict__ src, int* __restrict__ cnt, int E)
{
    int e = blockIdx.x * 256 + threadIdx.x;
    if (e < E) atomicAdd(&cnt[src[e]], 1);
}

__global__ __launch_bounds__(1024)
void scan_kernel(const int* __restrict__ cnt, int* __restrict__ row_start, int n)
{
    __shared__ int part[1024];
    int tid = threadIdx.x;
    int chunk = (n + 1023) >> 10;
    int b = tid * chunk;
    int e = min(b + chunk, n);
    int s = 0;
    for (int i = b; i < e; i++) s += cnt[i];
    part[tid] = s;
    __syncthreads();
    for (int off = 1; off < 1024; off <<= 1) {
        int v = (tid >= off) ? part[tid - off] : 0;
        __syncthreads();
        part[tid] += v;
        __syncthreads();
    }
    int excl = (tid == 0) ? 0 : part[tid - 1];
    for (int i = b; i < e; i++) { row_start[i] = excl; excl += cnt[i]; }
    if (tid == 1023) row_start[n] = part[1023];
}

__global__ void bucket_kernel(const int* __restrict__ src, int* __restrict__ cursor,
                              int* __restrict__ edge_ids, int E)
{
    int e = blockIdx.x * 256 + threadIdx.x;
    if (e < E) { int p = atomicAdd(&cursor[src[e]], 1); edge_ids[p] = e; }
}

// ---- slot setup ------------------------------------------------------------
__global__ void slotnode_kernel(const int* __restrict__ triples,
                                int* __restrict__ slotNode, int NS)
{
    int r = blockIdx.x * 256 + threadIdx.x;
    if (r < NS) { int b = r >> 1, p = (r & 1) * 2; slotNode[r] = triples[b * 3 + p]; }
}

__global__ void deg_kernel(const int* __restrict__ slotNode, const int* __restrict__ rowSt,
                           int* __restrict__ deg, int NS)
{
    int r = blockIdx.x * 256 + threadIdx.x;
    if (r < NS) { int n = slotNode[r]; deg[r] = rowSt[n + 1] - rowSt[n]; }
}

__global__ void fill_rows_kernel(const int* __restrict__ slotNode, const int* __restrict__ rowSt,
                                 const int* __restrict__ edgeIds, const int* __restrict__ slotOff,
                                 int* __restrict__ rows, int NS)
{
    int r = blockIdx.x * 256 + threadIdx.x;
    if (r >= NS) return;
    int n = slotNode[r];
    int gs = rowSt[n], d = rowSt[n + 1] - gs, mo = slotOff[r];
    for (int j = 0; j < d && mo + j < MAXM; j++) rows[mo + j] = edgeIds[gs + j];
}

// ---- exp(-leaky_relu(x,0.2)) in place -------------------------------------
__global__ void exp_kernel(float* __restrict__ s, int Mhost, const int* __restrict__ Mdev)
{
    int m = blockIdx.x * 256 + threadIdx.x;
    int M = Mdev ? min(MAXM, *Mdev) : Mhost;
    if (m < M) {
        float x = s[m];
        float lr = x >= 0.f ? x : 0.2f * x;
        s[m] = expf(-lr);
    }
}

// ---- tiled fp32 GEMM, 64x64 tiles, K=512 ----------------------------------
// AMODE 0: A row m = e0[dst[rows[m]]] * rel_emb[rel[rows[m]]]   (edge)
// AMODE 1: A row m = e0[slotNode[m]] * g0                        (slot base)
// AMODE 2: A row m = Adense[m]                                   (P)
// AMODE 3: A row m = e0[slotNode[m]]                              (ent)
// AMODE 4: A row m = Adense[m]                                   (rel_emb)
// BMODE 0: NT (@W1^T)    BMODE 1: NN (@WE/WR)
// EPI 0: store  EPI 1: score scatter (no store)  EPI 2: elu(acc*invDenom) store
// EPI 3: acc+Hadd store
template<int AMODE, int BMODE, int EPI, bool DEVM>
__global__ __launch_bounds__(256)
void gemm_k(const float* __restrict__ entEmb, const float* __restrict__ invNorm,
            const int* __restrict__ rowsList, const int* __restrict__ srcIdx,
            const int* __restrict__ dstIdx,  const int* __restrict__ relIdx,
            const float* __restrict__ relEmb, const float* __restrict__ g0,
            const int* __restrict__ slotNode, const float* __restrict__ Adense,
            const float* __restrict__ Bmat,   const float* __restrict__ Wa,
            float* __restrict__ scoreOut,     const float* __restrict__ invDenom,
            const float* __restrict__ Hadd,   float* __restrict__ Cout,
            int Mhost, const int* __restrict__ Mdev)
{
    __shared__ float As[KT][LDSP];
    __shared__ float Bs[KT][LDSP];
    int M = DEVM ? min(MAXM, *Mdev) : Mhost;
    int tid = threadIdx.x;
    int n0 = blockIdx.y * TILE;
    int tn = tid & 15, tm = tid >> 4;

    for (int mt = blockIdx.x; mt * TILE < M; mt += gridDim.x) {
        int m0 = mt * TILE;
        // ---- A staging pointers for this tile ----
        int aRow = tid >> 2, aKq = (tid & 3) * 4;
        int amc = min(m0 + aRow, M - 1);
        const float* aPtr = nullptr; const float* aPtr2 = nullptr;
        float aScale = 1.f;
        if (AMODE == 0) {
            int e = rowsList[amc];
            int dn = dstIdx[e], rn = relIdx[e];
            aPtr  = entEmb + (size_t)dn * DDIM + aKq;
            aPtr2 = relEmb + (size_t)rn * DDIM + aKq;
            aScale = invNorm[dn];
        } else if (AMODE == 1) {
            int n = slotNode[amc];
            aPtr  = entEmb + (size_t)n * DDIM + aKq;
            aPtr2 = g0 + aKq;
            aScale = invNorm[n];
        } else if (AMODE == 2 || AMODE == 4) {
            aPtr = Adense + (size_t)amc * DDIM + aKq;
        } else { // 3
            int n = slotNode[amc];
            aPtr = entEmb + (size_t)n * DDIM + aKq;
            aScale = invNorm[n];
        }
        // ---- B staging pointers ----
        const float* bPtr = nullptr;
        int bRow = 0, bK = 0, bN = 0;
        if (BMODE == 0) { bRow = tid >> 2; bK = (tid & 3) * 4; bPtr = Bmat + (size_t)(n0 + bRow) * DDIM + bK; }
        else            { bK = tid >> 4;  bN = (tid & 15) * 4; bPtr = Bmat + (size_t)bK * DDIM + n0 + bN; }

        float acc[4][4];
        #pragma unroll
        for (int i = 0; i < 4; i++)
            #pragma unroll
            for (int j = 0; j < 4; j++) acc[i][j] = 0.f;

        for (int kt = 0; kt < DDIM; kt += KT) {
            float4 va;
            {
                float4 x = *(const float4*)(aPtr + kt);
                if (AMODE == 0 || AMODE == 1) {
                    float4 y = *(const float4*)(aPtr2 + kt);
                    va = make_float4(x.x*y.x*aScale, x.y*y.y*aScale, x.z*y.z*aScale, x.w*y.w*aScale);
                } else if (AMODE == 3) {
                    va = make_float4(x.x*aScale, x.y*aScale, x.z*aScale, x.w*aScale);
                } else {
                    va = x;
                }
            }
            As[aKq+0][aRow] = va.x; As[aKq+1][aRow] = va.y;
            As[aKq+2][aRow] = va.z; As[aKq+3][aRow] = va.w;

            if (BMODE == 0) {
                float4 vb = *(const float4*)(bPtr + kt);
                Bs[bK+0][bRow] = vb.x; Bs[bK+1][bRow] = vb.y;
                Bs[bK+2][bRow] = vb.z; Bs[bK+3][bRow] = vb.w;
            } else {
                float4 vb = *(const float4*)(bPtr + (size_t)kt * DDIM);
                *(float4*)&Bs[bK][bN] = vb;
            }
            __syncthreads();

            #pragma unroll
            for (int k = 0; k < KT; k++) {
                float4 af = *(const float4*)&As[k][tm * 4];
                float4 bf = *(const float4*)&Bs[k][tn * 4];
                float a_[4] = {af.x, af.y, af.z, af.w};
                float b_[4] = {bf.x, bf.y, bf.z, bf.w};
                #pragma unroll
                for (int i = 0; i < 4; i++)
                    #pragma unroll
                    for (int j = 0; j < 4; j++)
                        acc[i][j] = fmaf(a_[i], b_[j], acc[i][j]);
            }
            __syncthreads();
        }

        // ---- epilogue ----
        if (EPI == 1) {
            #pragma unroll
            for (int i = 0; i < 4; i++) {
                int gm = m0 + tm * 4 + i;
                bool valid = gm < M;
                float s = 0.f;
                if (valid) {
                    int srcn = (AMODE == 0) ? srcIdx[rowsList[gm]] : slotNode[gm];
                    float invs = invNorm[srcn];
                    float4 h4 = *(const float4*)(entEmb + (size_t)srcn * DDIM + n0 + tn * 4);
                    float4 w4 = *(const float4*)(Wa + n0 + tn * 4);
                    s = tanhf(acc[i][0]) * h4.x * w4.x + tanhf(acc[i][1]) * h4.y * w4.y
                      + tanhf(acc[i][2]) * h4.z * w4.z + tanhf(acc[i][3]) * h4.w * w4.w;
                    s *= invs;
                }
                s += __shfl_down(s, 8); s += __shfl_down(s, 4);
                s += __shfl_down(s, 2); s += __shfl_down(s, 1);
                if (tn == 0 && valid) atomicAdd(scoreOut + gm, s);
            }
        } else {
            #pragma unroll
            for (int i = 0; i < 4; i++) {
                int gm = m0 + tm * 4 + i;
                if (gm < M) {
                    size_t o = (size_t)gm * DDIM + n0 + tn * 4;
                    float4 v = make_float4(acc[i][0], acc[i][1], acc[i][2], acc[i][3]);
                    if (EPI == 2) {
                        float idn = invDenom[gm];
                        v = make_float4(elu1(v.x*idn), elu1(v.y*idn), elu1(v.z*idn), elu1(v.w*idn));
                    } else if (EPI == 3) {
                        float4 h = *(const float4*)(Hadd + o);
                        v.x += h.x; v.y += h.y; v.z += h.z; v.w += h.w;
                    }
                    *(float4*)(Cout + o) = v;
                }
            }
        }
    }
}

// ---- P build: aggregate pre-GEMM rows + denom (CSR, no atomics) -----------
__global__ __launch_bounds__(128)
void build_p_kernel(const float* __restrict__ entEmb, const float* __restrict__ invNorm,
                    const float* __restrict__ relEmb, const float* __restrict__ g0,
                    const int* __restrict__ slotNode, const int* __restrict__ rowSt,
                    const int* __restrict__ edgeIds, const int* __restrict__ dstIdx,
                    const int* __restrict__ relIdx, const int* __restrict__ slotOff,
                    const float* __restrict__ aExpE, const float* __restrict__ abExpS,
                    float* __restrict__ P, float* __restrict__ invDenom)
{
    int r = blockIdx.x, t = threadIdx.x;
    int n = slotNode[r];
    int gs = rowSt[n], d = rowSt[n + 1] - gs;
    size_t po = (size_t)r * DDIM + t * 4;
    if (d == 0) {   // node never a src: h' = 0
        *(float4*)(P + po) = make_float4(0.f, 0.f, 0.f, 0.f);
        if (t == 0) invDenom[r] = 1.f;
        return;
    }
    int mo = slotOff[r];
    float ab = abExpS[r];
    float sc = ab * invNorm[n];
    float4 ev = *(const float4*)(entEmb + (size_t)n * DDIM + t * 4);
    float4 gv = *(const float4*)(g0 + t * 4);
    float4 acc = make_float4(sc*ev.x*gv.x, sc*ev.y*gv.y, sc*ev.z*gv.z, sc*ev.w*gv.w);
    float denom = ab;
    for (int j = 0; j < d; j++) {
        if (mo + j >= MAXM) break;
        int e = edgeIds[gs + j];
        float ae = aExpE[mo + j];
        int dn = dstIdx[e], rl = relIdx[e];
        float s = ae * invNorm[dn];
        float4 dv = *(const float4*)(entEmb + (size_t)dn * DDIM + t * 4);
        float4 rv = *(const float4*)(relEmb + (size_t)rl * DDIM + t * 4);
        acc.x = fmaf(s, dv.x*rv.x, acc.x);
        acc.y = fmaf(s, dv.y*rv.y, acc.y);
        acc.z = fmaf(s, dv.z*rv.z, acc.z);
        acc.w = fmaf(s, dv.w*rv.w, acc.w);
        denom += ae;
    }
    *(float4*)(P + po) = acc;
    if (t == 0) invDenom[r] = 1.f / denom;
}

// ---- final gather [B,3,512] ------------------------------------------------
__global__ __launch_bounds__(128)
void gather_out_kernel(const int* __restrict__ triples, const float* __restrict__ ENT,
                       const float* __restrict__ relnew, float* __restrict__ out)
{
    int r = blockIdx.x;          // b*3 + j
    int b = r / 3, j = r - b * 3;
    const float* srow;
    if (j == 1) srow = relnew + (size_t)triples[r] * DDIM;
    else        srow = ENT + (size_t)(b * 2 + (j == 2 ? 1 : 0)) * DDIM;
    int t = threadIdx.x * 4;
    *(float4*)(out + (size_t)r * DDIM + t) = *(const float4*)(srow + t);
}

// ---------------------------------------------------------------------------
extern "C" void kernel_launch(void* const* d_in, const int* in_sizes, int n_in,
                              void* d_out, int out_size, void* d_ws, size_t ws_size,
                              hipStream_t stream)
{
    const int*   triples = (const int*)  d_in[0];
    const int*   nodes   = (const int*)  d_in[1];
    const int*   edges   = (const int*)  d_in[2];
    const float* entEmb  = (const float*)d_in[3];
    const float* relEmb  = (const float*)d_in[4];
    const float* W1      = (const float*)d_in[5];
    const float* Wa      = (const float*)d_in[6];
    const float* g0      = (const float*)d_in[7];
    const float* WE      = (const float*)d_in[8];
    const float* WR      = (const float*)d_in[9];

    const int B  = in_sizes[0] / 3;
    const int E  = in_sizes[2];
    const int N  = in_sizes[3] / DDIM;
    const int R  = in_sizes[4] / DDIM;
    const int NS = 2 * B;
    const int* srcIdx = nodes;
    const int* dstIdx = nodes + E;

    // ---- workspace carve (~54 MB) ----
    char* ws = (char*)d_ws;
    size_t off = 0;
    auto carve = [&](size_t bytes) -> void* {
        void* p = ws + off;
        off = (off + bytes + 255) & ~(size_t)255;
        return p;
    };
    float* P        = (float*)carve((size_t)NS * DDIM * 4);
    float* H        = (float*)carve((size_t)NS * DDIM * 4);
    float* ENT      = (float*)carve((size_t)NS * DDIM * 4);
    float* relnew   = (float*)carve((size_t)R * DDIM * 4);
    float* invNorm  = (float*)carve((size_t)N * 4);
    float* score_e  = (float*)carve((size_t)MAXM * 4);   // -> a_exp in place
    float* score_s  = (float*)carve((size_t)NS * 4);     // -> ab_exp in place
    float* invDen   = (float*)carve((size_t)NS * 4);
    int*   cnt      = (int*)carve((size_t)N * 4);
    int*   rowSt    = (int*)carve((size_t)(N + 1) * 4);
    int*   cursor   = (int*)carve((size_t)N * 4);
    int*   edgeIds  = (int*)carve((size_t)E * 4);
    int*   slotNode = (int*)carve((size_t)NS * 4);
    int*   deg      = (int*)carve((size_t)NS * 4);
    int*   slotOff  = (int*)carve((size_t)(NS + 1) * 4);
    int*   rowsL    = (int*)carve((size_t)MAXM * 4);
    (void)ws_size; (void)n_in; (void)out_size;

    // 1. inverse norms
    invnorm_kernel<<<N, 128, 0, stream>>>(entEmb, invNorm);

    // 2. global CSR over src
    hipMemsetAsync(cnt, 0, (size_t)N * 4, stream);
    hist_kernel<<<(E + 255) / 256, 256, 0, stream>>>(srcIdx, cnt, E);
    scan_kernel<<<1, 1024, 0, stream>>>(cnt, rowSt, N);
    hipMemcpyAsync(cursor, rowSt, (size_t)N * 4, hipMemcpyDeviceToDevice, stream);
    bucket_kernel<<<(E + 255) / 256, 256, 0, stream>>>(srcIdx, cursor, edgeIds, E);

    // 3. slots: node ids, degrees, offsets, edge-row list
    slotnode_kernel<<<(NS + 255) / 256, 256, 0, stream>>>(triples, slotNode, NS);
    deg_kernel<<<(NS + 255) / 256, 256, 0, stream>>>(slotNode, rowSt, deg, NS);
    scan_kernel<<<1, 1024, 0, stream>>>(deg, slotOff, NS);
    fill_rows_kernel<<<(NS + 255) / 256, 256, 0, stream>>>(slotNode, rowSt, edgeIds,
                                                           slotOff, rowsL, NS);
    const int* Mdev = slotOff + NS;   // total selected edge-rows

    // 4. edge score GEMM (scores only; c never stored)
    hipMemsetAsync(score_e, 0, (size_t)MAXM * 4, stream);
    hipMemsetAsync(score_s, 0, (size_t)NS * 4, stream);
    dim3 gEdge(256, DDIM / TILE);
    gemm_k<0, 0, 1, true><<<gEdge, 256, 0, stream>>>(
        entEmb, invNorm, rowsL, srcIdx, dstIdx, edges, relEmb, g0, slotNode,
        nullptr, W1, Wa, score_e, nullptr, nullptr, nullptr, 0, Mdev);

    // 5. slot base score GEMM
    dim3 gSlot((NS + TILE - 1) / TILE, DDIM / TILE);
    gemm_k<1, 0, 1, false><<<gSlot, 256, 0, stream>>>(
        entEmb, invNorm, nullptr, nullptr, nullptr, nullptr, relEmb, g0, slotNode,
        nullptr, W1, Wa, score_s, nullptr, nullptr, nullptr, NS, nullptr);

    // 6. exp(-leaky)
    exp_kernel<<<(MAXM + 255) / 256, 256, 0, stream>>>(score_e, 0, Mdev);
    exp_kernel<<<(NS + 255) / 256, 256, 0, stream>>>(score_s, NS, nullptr);

    // 7. P + denominators
    build_p_kernel<<<NS, 128, 0, stream>>>(entEmb, invNorm, relEmb, g0, slotNode,
                                           rowSt, edgeIds, dstIdx, edges, slotOff,
                                           score_e, score_s, P, invDen);

    // 8. H = elu((P @ W1^T) * invDenom)
    gemm_k<2, 0, 2, false><<<gSlot, 256, 0, stream>>>(
        entEmb, invNorm, nullptr, nullptr, nullptr, nullptr, relEmb, g0, slotNode,
        P, W1, nullptr, nullptr, invDen, nullptr, H, NS, nullptr);

    // 9. ENT = e0[slot] @ WE + H ; l2norm in place
    gemm_k<3, 1, 3, false><<<gSlot, 256, 0, stream>>>(
        entEmb, invNorm, nullptr, nullptr, nullptr, nullptr, relEmb, g0, slotNode,
        nullptr, WE, nullptr, nullptr, nullptr, H, ENT, NS, nullptr);
    l2norm_kernel<<<NS, 128, 0, stream>>>(ENT);

    // 10. relnew = rel_emb @ WR
    dim3 gRel((R + TILE - 1) / TILE, DDIM / TILE);
    gemm_k<4, 1, 0, false><<<gRel, 256, 0, stream>>>(
        entEmb, invNorm, nullptr, nullptr, nullptr, nullptr, relEmb, g0, slotNode,
        relEmb, WR, nullptr, nullptr, nullptr, nullptr, relnew, R, nullptr);

    // 11. gather
    gather_out_kernel<<<B * 3, 128, 0, stream>>>(triples, ENT, relnew, (float*)d_out);
}

// Round 3
// 706.019 us; speedup vs baseline: 1.2032x; 1.2032x over previous
//
#include <hip/hip_runtime.h>
#include <cmath>

// ---------------------------------------------------------------------------
// UPGAT forward — gathered-rows restructure + parallel 3-phase scan.
//
// R3 changes vs R2:
//  * scan_kernel (single-block, 163us, 0.16% occupancy) -> 3-phase multi-block
//    scan (scan1/scan2/scan3), ~8us for N=100000.
//  * exp(-leaky) folded into build_p_kernel; exp_kernel launches removed.
//
// Pipeline:
//   1. inv_norm[n] = 1/max(||ent_emb[n]||,eps)         [N]
//   2. global CSR over src (hist -> 3-phase scan -> bucket)
//   3. slotNode[r], deg[r], slotOff scan, rows[m] per-slot edge ids (M~12K)
//   4. edge GEMM  (rows x 512 @ W1^T), EPI=score scatter -> score_e[M] (raw)
//   5. slot GEMM  (NS x 512 @ W1^T),  EPI=score scatter -> score_s[NS] (raw)
//   6. P[r] = ab*(e0.g0) + sum a_e*(e0[dst].g_rel); inv_denom[r]  (exp inline)
//   7. hp GEMM:  H = elu((P @ W1^T) * inv_denom)
//   8. ent GEMM: ENT = e0[slot] @ WE + H; l2norm rows in place
//   9. rel GEMM: relnew = rel_emb @ WR
//  10. gather -> out [B,3,512]
// ---------------------------------------------------------------------------

#define DDIM 512
#define TILE 64
#define KT   16
#define LDSP 68
#define MAXM 65536   // bound on total selected edge-rows (expected ~12K)

__device__ __forceinline__ float elu1(float x) { return x > 0.f ? x : expm1f(x); }
// exp(-leaky_relu(x, 0.2))
__device__ __forceinline__ float sexp(float x) {
    float lr = x >= 0.f ? x : 0.2f * x;
    return expf(-lr);
}

// ---- inverse L2 norm per row ----------------------------------------------
__global__ __launch_bounds__(128)
void invnorm_kernel(const float* __restrict__ emb, float* __restrict__ invN)
{
    int r = blockIdx.x, t = threadIdx.x;
    float4 v = *(const float4*)(emb + (size_t)r * DDIM + t * 4);
    float s = v.x*v.x + v.y*v.y + v.z*v.z + v.w*v.w;
    #pragma unroll
    for (int off = 32; off > 0; off >>= 1) s += __shfl_down(s, off);
    __shared__ float ws[2];
    if ((t & 63) == 0) ws[t >> 6] = s;
    __syncthreads();
    if (t == 0) invN[r] = 1.f / fmaxf(sqrtf(ws[0] + ws[1]), 1e-12f);
}

// ---- row-wise L2 normalize in place ---------------------------------------
__global__ __launch_bounds__(128)
void l2norm_kernel(float* __restrict__ data)
{
    int r = blockIdx.x, t = threadIdx.x;
    size_t o = (size_t)r * DDIM + t * 4;
    float4 v = *(const float4*)(data + o);
    float s = v.x*v.x + v.y*v.y + v.z*v.z + v.w*v.w;
    #pragma unroll
    for (int off = 32; off > 0; off >>= 1) s += __shfl_down(s, off);
    __shared__ float ws[2];
    if ((t & 63) == 0) ws[t >> 6] = s;
    __syncthreads();
    float inv = 1.f / fmaxf(sqrtf(ws[0] + ws[1]), 1e-12f);
    *(float4*)(data + o) = make_float4(v.x*inv, v.y*inv, v.z*inv, v.w*inv);
}

// ---- CSR build over src ----------------------------------------------------
__global__ void hist_kernel(const int* __restrict__ src, int* __restrict__ cnt, int E)
{
    int e = blockIdx.x * 256 + threadIdx.x;
    if (e < E) atomicAdd(&cnt[src[e]], 1);
}

// ---- 3-phase parallel exclusive scan (n <= 1024*1024) ---------------------
__global__ __launch_bounds__(1024)
void scan1_kernel(const int* __restrict__ in, int* __restrict__ out,
                  int* __restrict__ blockTot, int n)
{
    __shared__ int sh[1024];
    int t = threadIdx.x;
    int i = blockIdx.x * 1024 + t;
    int v = (i < n) ? in[i] : 0;
    sh[t] = v;
    __syncthreads();
    for (int off = 1; off < 1024; off <<= 1) {
        int x = (t >= off) ? sh[t - off] : 0;
        __syncthreads();
        sh[t] += x;
        __syncthreads();
    }
    if (i < n) out[i] = sh[t] - v;               // exclusive within block
    if (t == 1023) blockTot[blockIdx.x] = sh[1023];
}

__global__ __launch_bounds__(1024)
void scan2_kernel(const int* __restrict__ blockTot, int* __restrict__ blockOff,
                  int* __restrict__ outLast, int G)
{
    __shared__ int sh[1024];
    int t = threadIdx.x;
    int v = (t < G) ? blockTot[t] : 0;
    sh[t] = v;
    __syncthreads();
    for (int off = 1; off < 1024; off <<= 1) {
        int x = (t >= off) ? sh[t - off] : 0;
        __syncthreads();
        sh[t] += x;
        __syncthreads();
    }
    if (t < G) blockOff[t] = sh[t] - v;          // exclusive block offsets
    if (t == 1023) *outLast = sh[1023];          // grand total -> out[n]
}

__global__ __launch_bounds__(1024)
void scan3_kernel(int* __restrict__ out, const int* __restrict__ blockOff, int n)
{
    int i = blockIdx.x * 1024 + threadIdx.x;
    if (i < n) out[i] += blockOff[blockIdx.x];
}

__global__ void bucket_kernel(const int* __restrict__ src, int* __restrict__ cursor,
                              int* __restrict__ edge_ids, int E)
{
    int e = blockIdx.x * 256 + threadIdx.x;
    if (e < E) { int p = atomicAdd(&cursor[src[e]], 1); edge_ids[p] = e; }
}

// ---- slot setup ------------------------------------------------------------
__global__ void slotnode_kernel(const int* __restrict__ triples,
                                int* __restrict__ slotNode, int NS)
{
    int r = blockIdx.x * 256 + threadIdx.x;
    if (r < NS) { int b = r >> 1, p = (r & 1) * 2; slotNode[r] = triples[b * 3 + p]; }
}

__global__ void deg_kernel(const int* __restrict__ slotNode, const int* __restrict__ rowSt,
                           int* __restrict__ deg, int NS)
{
    int r = blockIdx.x * 256 + threadIdx.x;
    if (r < NS) { int n = slotNode[r]; deg[r] = rowSt[n + 1] - rowSt[n]; }
}

__global__ void fill_rows_kernel(const int* __restrict__ slotNode, const int* __restrict__ rowSt,
                                 const int* __restrict__ edgeIds, const int* __restrict__ slotOff,
                                 int* __restrict__ rows, int NS)
{
    int r = blockIdx.x * 256 + threadIdx.x;
    if (r >= NS) return;
    int n = slotNode[r];
    int gs = rowSt[n], d = rowSt[n + 1] - gs, mo = slotOff[r];
    for (int j = 0; j < d && mo + j < MAXM; j++) rows[mo + j] = edgeIds[gs + j];
}

// ---- tiled fp32 GEMM, 64x64 tiles, K=512 ----------------------------------
// AMODE 0: A row m = e0[dst[rows[m]]] * rel_emb[rel[rows[m]]]   (edge)
// AMODE 1: A row m = e0[slotNode[m]] * g0                        (slot base)
// AMODE 2: A row m = Adense[m]                                   (P)
// AMODE 3: A row m = e0[slotNode[m]]                              (ent)
// AMODE 4: A row m = Adense[m]                                   (rel_emb)
// BMODE 0: NT (@W1^T)    BMODE 1: NN (@WE/WR)
// EPI 0: store  EPI 1: score scatter (no store)  EPI 2: elu(acc*invDenom) store
// EPI 3: acc+Hadd store
template<int AMODE, int BMODE, int EPI, bool DEVM>
__global__ __launch_bounds__(256)
void gemm_k(const float* __restrict__ entEmb, const float* __restrict__ invNorm,
            const int* __restrict__ rowsList, const int* __restrict__ srcIdx,
            const int* __restrict__ dstIdx,  const int* __restrict__ relIdx,
            const float* __restrict__ relEmb, const float* __restrict__ g0,
            const int* __restrict__ slotNode, const float* __restrict__ Adense,
            const float* __restrict__ Bmat,   const float* __restrict__ Wa,
            float* __restrict__ scoreOut,     const float* __restrict__ invDenom,
            const float* __restrict__ Hadd,   float* __restrict__ Cout,
            int Mhost, const int* __restrict__ Mdev)
{
    __shared__ float As[KT][LDSP];
    __shared__ float Bs[KT][LDSP];
    int M = DEVM ? min(MAXM, *Mdev) : Mhost;
    int tid = threadIdx.x;
    int n0 = blockIdx.y * TILE;
    int tn = tid & 15, tm = tid >> 4;

    for (int mt = blockIdx.x; mt * TILE < M; mt += gridDim.x) {
        int m0 = mt * TILE;
        // ---- A staging pointers for this tile ----
        int aRow = tid >> 2, aKq = (tid & 3) * 4;
        int amc = min(m0 + aRow, M - 1);
        const float* aPtr = nullptr; const float* aPtr2 = nullptr;
        float aScale = 1.f;
        if (AMODE == 0) {
            int e = rowsList[amc];
            int dn = dstIdx[e], rn = relIdx[e];
            aPtr  = entEmb + (size_t)dn * DDIM + aKq;
            aPtr2 = relEmb + (size_t)rn * DDIM + aKq;
            aScale = invNorm[dn];
        } else if (AMODE == 1) {
            int n = slotNode[amc];
            aPtr  = entEmb + (size_t)n * DDIM + aKq;
            aPtr2 = g0 + aKq;
            aScale = invNorm[n];
        } else if (AMODE == 2 || AMODE == 4) {
            aPtr = Adense + (size_t)amc * DDIM + aKq;
        } else { // 3
            int n = slotNode[amc];
            aPtr = entEmb + (size_t)n * DDIM + aKq;
            aScale = invNorm[n];
        }
        // ---- B staging pointers ----
        const float* bPtr = nullptr;
        int bRow = 0, bK = 0, bN = 0;
        if (BMODE == 0) { bRow = tid >> 2; bK = (tid & 3) * 4; bPtr = Bmat + (size_t)(n0 + bRow) * DDIM + bK; }
        else            { bK = tid >> 4;  bN = (tid & 15) * 4; bPtr = Bmat + (size_t)bK * DDIM + n0 + bN; }

        float acc[4][4];
        #pragma unroll
        for (int i = 0; i < 4; i++)
            #pragma unroll
            for (int j = 0; j < 4; j++) acc[i][j] = 0.f;

        for (int kt = 0; kt < DDIM; kt += KT) {
            float4 va;
            {
                float4 x = *(const float4*)(aPtr + kt);
                if (AMODE == 0 || AMODE == 1) {
                    float4 y = *(const float4*)(aPtr2 + kt);
                    va = make_float4(x.x*y.x*aScale, x.y*y.y*aScale, x.z*y.z*aScale, x.w*y.w*aScale);
                } else if (AMODE == 3) {
                    va = make_float4(x.x*aScale, x.y*aScale, x.z*aScale, x.w*aScale);
                } else {
                    va = x;
                }
            }
            As[aKq+0][aRow] = va.x; As[aKq+1][aRow] = va.y;
            As[aKq+2][aRow] = va.z; As[aKq+3][aRow] = va.w;

            if (BMODE == 0) {
                float4 vb = *(const float4*)(bPtr + kt);
                Bs[bK+0][bRow] = vb.x; Bs[bK+1][bRow] = vb.y;
                Bs[bK+2][bRow] = vb.z; Bs[bK+3][bRow] = vb.w;
            } else {
                float4 vb = *(const float4*)(bPtr + (size_t)kt * DDIM);
                *(float4*)&Bs[bK][bN] = vb;
            }
            __syncthreads();

            #pragma unroll
            for (int k = 0; k < KT; k++) {
                float4 af = *(const float4*)&As[k][tm * 4];
                float4 bf = *(const float4*)&Bs[k][tn * 4];
                float a_[4] = {af.x, af.y, af.z, af.w};
                float b_[4] = {bf.x, bf.y, bf.z, bf.w};
                #pragma unroll
                for (int i = 0; i < 4; i++)
                    #pragma unroll
                    for (int j = 0; j < 4; j++)
                        acc[i][j] = fmaf(a_[i], b_[j], acc[i][j]);
            }
            __syncthreads();
        }

        // ---- epilogue ----
        if (EPI == 1) {
            #pragma unroll
            for (int i = 0; i < 4; i++) {
                int gm = m0 + tm * 4 + i;
                bool valid = gm < M;
                float s = 0.f;
                if (valid) {
                    int srcn = (AMODE == 0) ? srcIdx[rowsList[gm]] : slotNode[gm];
                    float invs = invNorm[srcn];
                    float4 h4 = *(const float4*)(entEmb + (size_t)srcn * DDIM + n0 + tn * 4);
                    float4 w4 = *(const float4*)(Wa + n0 + tn * 4);
                    s = tanhf(acc[i][0]) * h4.x * w4.x + tanhf(acc[i][1]) * h4.y * w4.y
                      + tanhf(acc[i][2]) * h4.z * w4.z + tanhf(acc[i][3]) * h4.w * w4.w;
                    s *= invs;
                }
                s += __shfl_down(s, 8); s += __shfl_down(s, 4);
                s += __shfl_down(s, 2); s += __shfl_down(s, 1);
                if (tn == 0 && valid) atomicAdd(scoreOut + gm, s);
            }
        } else {
            #pragma unroll
            for (int i = 0; i < 4; i++) {
                int gm = m0 + tm * 4 + i;
                if (gm < M) {
                    size_t o = (size_t)gm * DDIM + n0 + tn * 4;
                    float4 v = make_float4(acc[i][0], acc[i][1], acc[i][2], acc[i][3]);
                    if (EPI == 2) {
                        float idn = invDenom[gm];
                        v = make_float4(elu1(v.x*idn), elu1(v.y*idn), elu1(v.z*idn), elu1(v.w*idn));
                    } else if (EPI == 3) {
                        float4 h = *(const float4*)(Hadd + o);
                        v.x += h.x; v.y += h.y; v.z += h.z; v.w += h.w;
                    }
                    *(float4*)(Cout + o) = v;
                }
            }
        }
    }
}

// ---- P build: aggregate pre-GEMM rows + denom (exp applied inline) --------
__global__ __launch_bounds__(128)
void build_p_kernel(const float* __restrict__ entEmb, const float* __restrict__ invNorm,
                    const float* __restrict__ relEmb, const float* __restrict__ g0,
                    const int* __restrict__ slotNode, const int* __restrict__ rowSt,
                    const int* __restrict__ edgeIds, const int* __restrict__ dstIdx,
                    const int* __restrict__ relIdx, const int* __restrict__ slotOff,
                    const float* __restrict__ scoreE, const float* __restrict__ scoreS,
                    float* __restrict__ P, float* __restrict__ invDenom)
{
    int r = blockIdx.x, t = threadIdx.x;
    int n = slotNode[r];
    int gs = rowSt[n], d = rowSt[n + 1] - gs;
    size_t po = (size_t)r * DDIM + t * 4;
    if (d == 0) {   // node never a src: h' = 0
        *(float4*)(P + po) = make_float4(0.f, 0.f, 0.f, 0.f);
        if (t == 0) invDenom[r] = 1.f;
        return;
    }
    int mo = slotOff[r];
    float ab = sexp(scoreS[r]);
    float sc = ab * invNorm[n];
    float4 ev = *(const float4*)(entEmb + (size_t)n * DDIM + t * 4);
    float4 gv = *(const float4*)(g0 + t * 4);
    float4 acc = make_float4(sc*ev.x*gv.x, sc*ev.y*gv.y, sc*ev.z*gv.z, sc*ev.w*gv.w);
    float denom = ab;
    for (int j = 0; j < d; j++) {
        if (mo + j >= MAXM) break;
        int e = edgeIds[gs + j];
        float ae = sexp(scoreE[mo + j]);
        int dn = dstIdx[e], rl = relIdx[e];
        float s = ae * invNorm[dn];
        float4 dv = *(const float4*)(entEmb + (size_t)dn * DDIM + t * 4);
        float4 rv = *(const float4*)(relEmb + (size_t)rl * DDIM + t * 4);
        acc.x = fmaf(s, dv.x*rv.x, acc.x);
        acc.y = fmaf(s, dv.y*rv.y, acc.y);
        acc.z = fmaf(s, dv.z*rv.z, acc.z);
        acc.w = fmaf(s, dv.w*rv.w, acc.w);
        denom += ae;
    }
    *(float4*)(P + po) = acc;
    if (t == 0) invDenom[r] = 1.f / denom;
}

// ---- final gather [B,3,512] ------------------------------------------------
__global__ __launch_bounds__(128)
void gather_out_kernel(const int* __restrict__ triples, const float* __restrict__ ENT,
                       const float* __restrict__ relnew, float* __restrict__ out)
{
    int r = blockIdx.x;          // b*3 + j
    int b = r / 3, j = r - b * 3;
    const float* srow;
    if (j == 1) srow = relnew + (size_t)triples[r] * DDIM;
    else        srow = ENT + (size_t)(b * 2 + (j == 2 ? 1 : 0)) * DDIM;
    int t = threadIdx.x * 4;
    *(float4*)(out + (size_t)r * DDIM + t) = *(const float4*)(srow + t);
}

// ---------------------------------------------------------------------------
extern "C" void kernel_launch(void* const* d_in, const int* in_sizes, int n_in,
                              void* d_out, int out_size, void* d_ws, size_t ws_size,
                              hipStream_t stream)
{
    const int*   triples = (const int*)  d_in[0];
    const int*   nodes   = (const int*)  d_in[1];
    const int*   edges   = (const int*)  d_in[2];
    const float* entEmb  = (const float*)d_in[3];
    const float* relEmb  = (const float*)d_in[4];
    const float* W1      = (const float*)d_in[5];
    const float* Wa      = (const float*)d_in[6];
    const float* g0      = (const float*)d_in[7];
    const float* WE      = (const float*)d_in[8];
    const float* WR      = (const float*)d_in[9];

    const int B  = in_sizes[0] / 3;
    const int E  = in_sizes[2];
    const int N  = in_sizes[3] / DDIM;
    const int R  = in_sizes[4] / DDIM;
    const int NS = 2 * B;
    const int* srcIdx = nodes;
    const int* dstIdx = nodes + E;

    // ---- workspace carve (~54 MB) ----
    char* ws = (char*)d_ws;
    size_t off = 0;
    auto carve = [&](size_t bytes) -> void* {
        void* p = ws + off;
        off = (off + bytes + 255) & ~(size_t)255;
        return p;
    };
    float* P        = (float*)carve((size_t)NS * DDIM * 4);
    float* H        = (float*)carve((size_t)NS * DDIM * 4);
    float* ENT      = (float*)carve((size_t)NS * DDIM * 4);
    float* relnew   = (float*)carve((size_t)R * DDIM * 4);
    float* invNorm  = (float*)carve((size_t)N * 4);
    float* score_e  = (float*)carve((size_t)MAXM * 4);
    float* score_s  = (float*)carve((size_t)NS * 4);
    float* invDen   = (float*)carve((size_t)NS * 4);
    int*   cnt      = (int*)carve((size_t)N * 4);
    int*   rowSt    = (int*)carve((size_t)(N + 1) * 4);
    int*   cursor   = (int*)carve((size_t)N * 4);
    int*   edgeIds  = (int*)carve((size_t)E * 4);
    int*   slotNode = (int*)carve((size_t)NS * 4);
    int*   deg      = (int*)carve((size_t)NS * 4);
    int*   slotOff  = (int*)carve((size_t)(NS + 1) * 4);
    int*   rowsL    = (int*)carve((size_t)MAXM * 4);
    int*   blockTot = (int*)carve((size_t)1024 * 4);
    int*   blockOff = (int*)carve((size_t)1024 * 4);
    (void)ws_size; (void)n_in; (void)out_size;

    // parallel exclusive scan: in[n] -> out[n+1]
    auto scan = [&](const int* in, int* out, int n) {
        int G = (n + 1023) / 1024;
        scan1_kernel<<<G, 1024, 0, stream>>>(in, out, blockTot, n);
        scan2_kernel<<<1, 1024, 0, stream>>>(blockTot, blockOff, out + n, G);
        scan3_kernel<<<G, 1024, 0, stream>>>(out, blockOff, n);
    };

    // 1. inverse norms
    invnorm_kernel<<<N, 128, 0, stream>>>(entEmb, invNorm);

    // 2. global CSR over src
    hipMemsetAsync(cnt, 0, (size_t)N * 4, stream);
    hist_kernel<<<(E + 255) / 256, 256, 0, stream>>>(srcIdx, cnt, E);
    scan(cnt, rowSt, N);
    hipMemcpyAsync(cursor, rowSt, (size_t)N * 4, hipMemcpyDeviceToDevice, stream);
    bucket_kernel<<<(E + 255) / 256, 256, 0, stream>>>(srcIdx, cursor, edgeIds, E);

    // 3. slots: node ids, degrees, offsets, edge-row list
    slotnode_kernel<<<(NS + 255) / 256, 256, 0, stream>>>(triples, slotNode, NS);
    deg_kernel<<<(NS + 255) / 256, 256, 0, stream>>>(slotNode, rowSt, deg, NS);
    scan(deg, slotOff, NS);
    fill_rows_kernel<<<(NS + 255) / 256, 256, 0, stream>>>(slotNode, rowSt, edgeIds,
                                                           slotOff, rowsL, NS);
    const int* Mdev = slotOff + NS;   // total selected edge-rows

    // 4. edge score GEMM (raw scores; c never stored)
    hipMemsetAsync(score_e, 0, (size_t)MAXM * 4, stream);
    hipMemsetAsync(score_s, 0, (size_t)NS * 4, stream);
    dim3 gEdge(256, DDIM / TILE);
    gemm_k<0, 0, 1, true><<<gEdge, 256, 0, stream>>>(
        entEmb, invNorm, rowsL, srcIdx, dstIdx, edges, relEmb, g0, slotNode,
        nullptr, W1, Wa, score_e, nullptr, nullptr, nullptr, 0, Mdev);

    // 5. slot base score GEMM (raw scores)
    dim3 gSlot((NS + TILE - 1) / TILE, DDIM / TILE);
    gemm_k<1, 0, 1, false><<<gSlot, 256, 0, stream>>>(
        entEmb, invNorm, nullptr, nullptr, nullptr, nullptr, relEmb, g0, slotNode,
        nullptr, W1, Wa, score_s, nullptr, nullptr, nullptr, NS, nullptr);

    // 6. P + denominators (exp inline)
    build_p_kernel<<<NS, 128, 0, stream>>>(entEmb, invNorm, relEmb, g0, slotNode,
                                           rowSt, edgeIds, dstIdx, edges, slotOff,
                                           score_e, score_s, P, invDen);

    // 7. H = elu((P @ W1^T) * invDenom)
    gemm_k<2, 0, 2, false><<<gSlot, 256, 0, stream>>>(
        entEmb, invNorm, nullptr, nullptr, nullptr, nullptr, relEmb, g0, slotNode,
        P, W1, nullptr, nullptr, invDen, nullptr, H, NS, nullptr);

    // 8. ENT = e0[slot] @ WE + H ; l2norm in place
    gemm_k<3, 1, 3, false><<<gSlot, 256, 0, stream>>>(
        entEmb, invNorm, nullptr, nullptr, nullptr, nullptr, relEmb, g0, slotNode,
        nullptr, WE, nullptr, nullptr, nullptr, H, ENT, NS, nullptr);
    l2norm_kernel<<<NS, 128, 0, stream>>>(ENT);

    // 9. relnew = rel_emb @ WR
    dim3 gRel((R + TILE - 1) / TILE, DDIM / TILE);
    gemm_k<4, 1, 0, false><<<gRel, 256, 0, stream>>>(
        entEmb, invNorm, nullptr, nullptr, nullptr, nullptr, relEmb, g0, slotNode,
        relEmb, WR, nullptr, nullptr, nullptr, nullptr, relnew, R, nullptr);

    // 10. gather
    gather_out_kernel<<<B * 3, 128, 0, stream>>>(triples, ENT, relnew, (float*)d_out);
}

// Round 4
// 516.349 us; speedup vs baseline: 1.6452x; 1.3673x over previous
//
#include <hip/hip_runtime.h>
#include <cmath>

// ---------------------------------------------------------------------------
// UPGAT forward — gathered-rows + split-bf16 MFMA GEMMs.
//
// R4 changes vs R3:
//  * All 5 GEMMs -> MFMA (v_mfma_f32_16x16x32_bf16) with split-bf16 A,B:
//      a = hi + lo (bf16 each); acc += hi*hi + hi*lo + lo*hi  (~fp32 accuracy,
//      3x bf16 MFMA cost; ceiling ~800 TF useful vs 157 TF fp32 VALU).
//    Verified layouts: A[m=lane&15][k=(lane>>4)*8+j]; C/D col=lane&15,
//    row=(lane>>4)*4+reg.  Block 64x64, BK=32, 4 waves in 2x2, 2x2 16x16
//    tiles/wave.
//  * WE, WR pre-transposed once so every GEMM is NT (k-contiguous staging).
//  * invnorm computed only for referenced rows (slots + dst of selected
//    edges ~20K of 100K): 205 MB -> ~40 MB.
//
// Pipeline:
//   1. CSR over src (hist -> 3-phase scan -> bucket)
//   2. slotNode/deg/slotOff/rowsL  (M ~ 12K selected edge-rows)
//   3. invnorm_sel over referenced rows
//   4. transpose WE, WR
//   5. edge GEMM (EPI=score) -> score_e ; slot GEMM (EPI=score) -> score_s
//   6. build_p: P[r] = ab*(e0.g0) + sum a_e*(e0[dst].g_rel); invDenom
//   7. H = elu((P @ W1^T) * invDenom)   [EPI 2]
//   8. ENT = e0[slot] @ WE + H [EPI 3]; l2norm
//   9. relnew = rel_emb @ WR   [EPI 0]
//  10. gather -> out [B,3,512]
// ---------------------------------------------------------------------------

#define DDIM 512
#define MAXM 65536
#define BM 64
#define BN 64
#define BK 32
#define LSTR 40   // LDS row stride in ushorts (32 + 8 pad -> 80B, 16B aligned)

typedef __attribute__((ext_vector_type(8))) short short8;
typedef __attribute__((ext_vector_type(4))) float fv4;

__device__ __forceinline__ float elu1(float x) { return x > 0.f ? x : expm1f(x); }
__device__ __forceinline__ float sexp(float x) {
    float lr = x >= 0.f ? x : 0.2f * x;
    return expf(-lr);
}
// round-to-nearest-even fp32 -> bf16 bits
__device__ __forceinline__ unsigned short f2bf(float x) {
    unsigned u = __float_as_uint(x);
    u += 0x7FFFu + ((u >> 16) & 1u);
    return (unsigned short)(u >> 16);
}
__device__ __forceinline__ float bf2f(unsigned short h) {
    return __uint_as_float((unsigned)h << 16);
}

// ---- inverse L2 norm, only for referenced rows (dup writes benign) --------
__global__ __launch_bounds__(128)
void invnorm_sel_kernel(const float* __restrict__ emb, const int* __restrict__ slotNode,
                        const int* __restrict__ rowsL, const int* __restrict__ dstIdx,
                        const int* __restrict__ Mdev, int NS, float* __restrict__ invN)
{
    __shared__ float ws2[2];
    int total = NS + min(MAXM, *Mdev);
    int t = threadIdx.x;
    for (int q = blockIdx.x; q < total; q += gridDim.x) {
        int n = (q < NS) ? slotNode[q] : dstIdx[rowsL[q - NS]];
        float4 v = *(const float4*)(emb + (size_t)n * DDIM + t * 4);
        float s = v.x*v.x + v.y*v.y + v.z*v.z + v.w*v.w;
        #pragma unroll
        for (int off = 32; off > 0; off >>= 1) s += __shfl_down(s, off);
        if ((t & 63) == 0) ws2[t >> 6] = s;
        __syncthreads();
        if (t == 0) invN[n] = 1.f / fmaxf(sqrtf(ws2[0] + ws2[1]), 1e-12f);
        __syncthreads();
    }
}

// ---- row-wise L2 normalize in place ---------------------------------------
__global__ __launch_bounds__(128)
void l2norm_kernel(float* __restrict__ data)
{
    int r = blockIdx.x, t = threadIdx.x;
    size_t o = (size_t)r * DDIM + t * 4;
    float4 v = *(const float4*)(data + o);
    float s = v.x*v.x + v.y*v.y + v.z*v.z + v.w*v.w;
    #pragma unroll
    for (int off = 32; off > 0; off >>= 1) s += __shfl_down(s, off);
    __shared__ float ws2[2];
    if ((t & 63) == 0) ws2[t >> 6] = s;
    __syncthreads();
    float inv = 1.f / fmaxf(sqrtf(ws2[0] + ws2[1]), 1e-12f);
    *(float4*)(data + o) = make_float4(v.x*inv, v.y*inv, v.z*inv, v.w*inv);
}

// ---- 512x512 transpose -----------------------------------------------------
__global__ __launch_bounds__(256)
void transpose512_kernel(const float* __restrict__ in, float* __restrict__ out)
{
    __shared__ float tile[32][33];
    int bx = blockIdx.x & 15, by = blockIdx.x >> 4;
    int x = threadIdx.x & 31, y0 = (threadIdx.x >> 5) * 4;
    #pragma unroll
    for (int i = 0; i < 4; i++)
        tile[y0 + i][x] = in[(size_t)(by * 32 + y0 + i) * 512 + bx * 32 + x];
    __syncthreads();
    #pragma unroll
    for (int i = 0; i < 4; i++)
        out[(size_t)(bx * 32 + y0 + i) * 512 + by * 32 + x] = tile[x][y0 + i];
}

// ---- CSR build over src ----------------------------------------------------
__global__ void hist_kernel(const int* __restrict__ src, int* __restrict__ cnt, int E)
{
    int e = blockIdx.x * 256 + threadIdx.x;
    if (e < E) atomicAdd(&cnt[src[e]], 1);
}

__global__ __launch_bounds__(1024)
void scan1_kernel(const int* __restrict__ in, int* __restrict__ out,
                  int* __restrict__ blockTot, int n)
{
    __shared__ int sh[1024];
    int t = threadIdx.x;
    int i = blockIdx.x * 1024 + t;
    int v = (i < n) ? in[i] : 0;
    sh[t] = v;
    __syncthreads();
    for (int off = 1; off < 1024; off <<= 1) {
        int x = (t >= off) ? sh[t - off] : 0;
        __syncthreads();
        sh[t] += x;
        __syncthreads();
    }
    if (i < n) out[i] = sh[t] - v;
    if (t == 1023) blockTot[blockIdx.x] = sh[1023];
}

__global__ __launch_bounds__(1024)
void scan2_kernel(const int* __restrict__ blockTot, int* __restrict__ blockOff,
                  int* __restrict__ outLast, int G)
{
    __shared__ int sh[1024];
    int t = threadIdx.x;
    int v = (t < G) ? blockTot[t] : 0;
    sh[t] = v;
    __syncthreads();
    for (int off = 1; off < 1024; off <<= 1) {
        int x = (t >= off) ? sh[t - off] : 0;
        __syncthreads();
        sh[t] += x;
        __syncthreads();
    }
    if (t < G) blockOff[t] = sh[t] - v;
    if (t == 1023) *outLast = sh[1023];
}

__global__ __launch_bounds__(1024)
void scan3_kernel(int* __restrict__ out, const int* __restrict__ blockOff, int n)
{
    int i = blockIdx.x * 1024 + threadIdx.x;
    if (i < n) out[i] += blockOff[blockIdx.x];
}

__global__ void bucket_kernel(const int* __restrict__ src, int* __restrict__ cursor,
                              int* __restrict__ edge_ids, int E)
{
    int e = blockIdx.x * 256 + threadIdx.x;
    if (e < E) { int p = atomicAdd(&cursor[src[e]], 1); edge_ids[p] = e; }
}

// ---- slot setup ------------------------------------------------------------
__global__ void slotnode_kernel(const int* __restrict__ triples,
                                int* __restrict__ slotNode, int NS)
{
    int r = blockIdx.x * 256 + threadIdx.x;
    if (r < NS) { int b = r >> 1, p = (r & 1) * 2; slotNode[r] = triples[b * 3 + p]; }
}

__global__ void deg_kernel(const int* __restrict__ slotNode, const int* __restrict__ rowSt,
                           int* __restrict__ deg, int NS)
{
    int r = blockIdx.x * 256 + threadIdx.x;
    if (r < NS) { int n = slotNode[r]; deg[r] = rowSt[n + 1] - rowSt[n]; }
}

__global__ void fill_rows_kernel(const int* __restrict__ slotNode, const int* __restrict__ rowSt,
                                 const int* __restrict__ edgeIds, const int* __restrict__ slotOff,
                                 int* __restrict__ rows, int NS)
{
    int r = blockIdx.x * 256 + threadIdx.x;
    if (r >= NS) return;
    int n = slotNode[r];
    int gs = rowSt[n], d = rowSt[n + 1] - gs, mo = slotOff[r];
    for (int j = 0; j < d && mo + j < MAXM; j++) rows[mo + j] = edgeIds[gs + j];
}

// ---- split-bf16 MFMA GEMM: C[M,512] = A[M,512] @ B^T (B NT, k-contig) -----
// AMODE 0: A row m = e0[dst[rows[m]]] * rel_emb[rel[rows[m]]]
// AMODE 1: A row m = e0[slotNode[m]] * g0
// AMODE 2: A row m = Adense[m]
// AMODE 3: A row m = e0[slotNode[m]]
// EPI 0: store   EPI 1: score scatter (atomicAdd, no store)
// EPI 2: elu(acc*invDenom) store      EPI 3: acc+Hadd store
template<int AMODE, int EPI, bool DEVM>
__global__ __launch_bounds__(256)
void gemm_mfma_k(const float* __restrict__ entEmb, const float* __restrict__ invNorm,
                 const int* __restrict__ rowsList, const int* __restrict__ srcIdx,
                 const int* __restrict__ dstIdx,  const int* __restrict__ relIdx,
                 const float* __restrict__ relEmb, const float* __restrict__ g0,
                 const int* __restrict__ slotNode, const float* __restrict__ Adense,
                 const float* __restrict__ Bmat,   const float* __restrict__ Wa,
                 float* __restrict__ scoreOut,     const float* __restrict__ invDenom,
                 const float* __restrict__ Hadd,   float* __restrict__ Cout,
                 int Mhost, const int* __restrict__ Mdev)
{
    __shared__ unsigned short AsH[BM][LSTR], AsL[BM][LSTR];
    __shared__ unsigned short BsH[BN][LSTR], BsL[BN][LSTR];

    int M = DEVM ? min(MAXM, *Mdev) : Mhost;
    int tid  = threadIdx.x;
    int lane = tid & 63, wid = tid >> 6;
    int waveM = wid >> 1, waveN = wid & 1;
    int quad = lane >> 4, l15 = lane & 15;
    int n0 = blockIdx.y * BN;

    // staging map: thread -> (row 0..63, k-seg 0/8/16/24)
    int sRow = tid >> 2;
    int sSeg = (tid & 3) * 8;

    for (int mt = blockIdx.x; mt * BM < M; mt += gridDim.x) {
        int m0 = mt * BM;
        int amc = min(m0 + sRow, M - 1);
        const float* aP = nullptr; const float* aP2 = nullptr;
        float aScale = 1.f;
        if (AMODE == 0) {
            int e = rowsList[amc];
            int dn = dstIdx[e], rn = relIdx[e];
            aP  = entEmb + (size_t)dn * DDIM + sSeg;
            aP2 = relEmb + (size_t)rn * DDIM + sSeg;
            aScale = invNorm[dn];
        } else if (AMODE == 1) {
            int n = slotNode[amc];
            aP  = entEmb + (size_t)n * DDIM + sSeg;
            aP2 = g0 + sSeg;
            aScale = invNorm[n];
        } else if (AMODE == 2) {
            aP = Adense + (size_t)amc * DDIM + sSeg;
        } else {
            int n = slotNode[amc];
            aP = entEmb + (size_t)n * DDIM + sSeg;
            aScale = invNorm[n];
        }
        const float* bP = Bmat + (size_t)(n0 + sRow) * DDIM + sSeg;

        fv4 acc[2][2];
        #pragma unroll
        for (int i = 0; i < 2; i++)
            #pragma unroll
            for (int j = 0; j < 2; j++) acc[i][j] = fv4{0.f, 0.f, 0.f, 0.f};

        for (int kt = 0; kt < DDIM; kt += BK) {
            __syncthreads();   // previous iter's LDS reads done
            // ---- stage A (8 floats -> hi/lo bf16) ----
            {
                float va[8];
                float4 x0 = *(const float4*)(aP + kt);
                float4 x1 = *(const float4*)(aP + kt + 4);
                va[0]=x0.x; va[1]=x0.y; va[2]=x0.z; va[3]=x0.w;
                va[4]=x1.x; va[5]=x1.y; va[6]=x1.z; va[7]=x1.w;
                if (AMODE == 0 || AMODE == 1) {
                    float4 y0 = *(const float4*)(aP2 + kt);
                    float4 y1 = *(const float4*)(aP2 + kt + 4);
                    va[0]*=y0.x; va[1]*=y0.y; va[2]*=y0.z; va[3]*=y0.w;
                    va[4]*=y1.x; va[5]*=y1.y; va[6]*=y1.z; va[7]*=y1.w;
                }
                short8 h8, l8;
                #pragma unroll
                for (int i = 0; i < 8; i++) {
                    float x = va[i] * aScale;
                    unsigned short h = f2bf(x);
                    h8[i] = (short)h;
                    l8[i] = (short)f2bf(x - bf2f(h));
                }
                *(short8*)&AsH[sRow][sSeg] = h8;
                *(short8*)&AsL[sRow][sSeg] = l8;
            }
            // ---- stage B ----
            {
                float4 x0 = *(const float4*)(bP + kt);
                float4 x1 = *(const float4*)(bP + kt + 4);
                float vb[8] = {x0.x,x0.y,x0.z,x0.w,x1.x,x1.y,x1.z,x1.w};
                short8 h8, l8;
                #pragma unroll
                for (int i = 0; i < 8; i++) {
                    unsigned short h = f2bf(vb[i]);
                    h8[i] = (short)h;
                    l8[i] = (short)f2bf(vb[i] - bf2f(h));
                }
                *(short8*)&BsH[sRow][sSeg] = h8;
                *(short8*)&BsL[sRow][sSeg] = l8;
            }
            __syncthreads();

            // ---- fragments + 12 MFMA ----
            short8 aH[2], aL[2], bH[2], bL[2];
            #pragma unroll
            for (int i = 0; i < 2; i++) {
                int ar = waveM * 32 + i * 16 + l15;
                aH[i] = *(const short8*)&AsH[ar][quad * 8];
                aL[i] = *(const short8*)&AsL[ar][quad * 8];
                int br = waveN * 32 + i * 16 + l15;
                bH[i] = *(const short8*)&BsH[br][quad * 8];
                bL[i] = *(const short8*)&BsL[br][quad * 8];
            }
            #pragma unroll
            for (int i = 0; i < 2; i++)
                #pragma unroll
                for (int j = 0; j < 2; j++) {
                    acc[i][j] = __builtin_amdgcn_mfma_f32_16x16x32_bf16(aH[i], bH[j], acc[i][j], 0, 0, 0);
                    acc[i][j] = __builtin_amdgcn_mfma_f32_16x16x32_bf16(aH[i], bL[j], acc[i][j], 0, 0, 0);
                    acc[i][j] = __builtin_amdgcn_mfma_f32_16x16x32_bf16(aL[i], bH[j], acc[i][j], 0, 0, 0);
                }
        }

        // ---- epilogue (C/D layout: col=lane&15, row=quad*4+reg) ----
        if (EPI == 1) {
            #pragma unroll
            for (int i = 0; i < 2; i++) {
                #pragma unroll
                for (int reg = 0; reg < 4; reg++) {
                    int gm = m0 + waveM * 32 + i * 16 + quad * 4 + reg;
                    bool valid = gm < M;
                    int gmc = valid ? gm : 0;
                    int srcn = (AMODE == 0) ? srcIdx[rowsList[gmc]] : slotNode[gmc];
                    float invs = invNorm[srcn];
                    float s = 0.f;
                    #pragma unroll
                    for (int j = 0; j < 2; j++) {
                        int col = n0 + waveN * 32 + j * 16 + l15;
                        float hv = entEmb[(size_t)srcn * DDIM + col];
                        float wv = Wa[col];
                        s += tanhf(acc[i][j][reg]) * hv * wv;
                    }
                    s *= invs;
                    s += __shfl_xor(s, 8); s += __shfl_xor(s, 4);
                    s += __shfl_xor(s, 2); s += __shfl_xor(s, 1);
                    if (l15 == 0 && valid) atomicAdd(scoreOut + gm, s);
                }
            }
        } else {
            #pragma unroll
            for (int i = 0; i < 2; i++) {
                #pragma unroll
                for (int reg = 0; reg < 4; reg++) {
                    int gm = m0 + waveM * 32 + i * 16 + quad * 4 + reg;
                    if (gm >= M) continue;
                    #pragma unroll
                    for (int j = 0; j < 2; j++) {
                        int col = n0 + waveN * 32 + j * 16 + l15;
                        size_t o = (size_t)gm * DDIM + col;
                        float v = acc[i][j][reg];
                        if (EPI == 2) v = elu1(v * invDenom[gm]);
                        else if (EPI == 3) v += Hadd[o];
                        Cout[o] = v;
                    }
                }
            }
        }
    }
}

// ---- P build: aggregate pre-GEMM rows + denom (exp inline) ----------------
__global__ __launch_bounds__(128)
void build_p_kernel(const float* __restrict__ entEmb, const float* __restrict__ invNorm,
                    const float* __restrict__ relEmb, const float* __restrict__ g0,
                    const int* __restrict__ slotNode, const int* __restrict__ rowSt,
                    const int* __restrict__ edgeIds, const int* __restrict__ dstIdx,
                    const int* __restrict__ relIdx, const int* __restrict__ slotOff,
                    const float* __restrict__ scoreE, const float* __restrict__ scoreS,
                    float* __restrict__ P, float* __restrict__ invDenom)
{
    int r = blockIdx.x, t = threadIdx.x;
    int n = slotNode[r];
    int gs = rowSt[n], d = rowSt[n + 1] - gs;
    size_t po = (size_t)r * DDIM + t * 4;
    if (d == 0) {
        *(float4*)(P + po) = make_float4(0.f, 0.f, 0.f, 0.f);
        if (t == 0) invDenom[r] = 1.f;
        return;
    }
    int mo = slotOff[r];
    float ab = sexp(scoreS[r]);
    float sc = ab * invNorm[n];
    float4 ev = *(const float4*)(entEmb + (size_t)n * DDIM + t * 4);
    float4 gv = *(const float4*)(g0 + t * 4);
    float4 acc = make_float4(sc*ev.x*gv.x, sc*ev.y*gv.y, sc*ev.z*gv.z, sc*ev.w*gv.w);
    float denom = ab;
    for (int j = 0; j < d; j++) {
        if (mo + j >= MAXM) break;
        int e = edgeIds[gs + j];
        float ae = sexp(scoreE[mo + j]);
        int dn = dstIdx[e], rl = relIdx[e];
        float s = ae * invNorm[dn];
        float4 dv = *(const float4*)(entEmb + (size_t)dn * DDIM + t * 4);
        float4 rv = *(const float4*)(relEmb + (size_t)rl * DDIM + t * 4);
        acc.x = fmaf(s, dv.x*rv.x, acc.x);
        acc.y = fmaf(s, dv.y*rv.y, acc.y);
        acc.z = fmaf(s, dv.z*rv.z, acc.z);
        acc.w = fmaf(s, dv.w*rv.w, acc.w);
        denom += ae;
    }
    *(float4*)(P + po) = acc;
    if (t == 0) invDenom[r] = 1.f / denom;
}

// ---- final gather [B,3,512] ------------------------------------------------
__global__ __launch_bounds__(128)
void gather_out_kernel(const int* __restrict__ triples, const float* __restrict__ ENT,
                       const float* __restrict__ relnew, float* __restrict__ out)
{
    int r = blockIdx.x;
    int b = r / 3, j = r - b * 3;
    const float* srow;
    if (j == 1) srow = relnew + (size_t)triples[r] * DDIM;
    else        srow = ENT + (size_t)(b * 2 + (j == 2 ? 1 : 0)) * DDIM;
    int t = threadIdx.x * 4;
    *(float4*)(out + (size_t)r * DDIM + t) = *(const float4*)(srow + t);
}

// ---------------------------------------------------------------------------
extern "C" void kernel_launch(void* const* d_in, const int* in_sizes, int n_in,
                              void* d_out, int out_size, void* d_ws, size_t ws_size,
                              hipStream_t stream)
{
    const int*   triples = (const int*)  d_in[0];
    const int*   nodes   = (const int*)  d_in[1];
    const int*   edges   = (const int*)  d_in[2];
    const float* entEmb  = (const float*)d_in[3];
    const float* relEmb  = (const float*)d_in[4];
    const float* W1      = (const float*)d_in[5];
    const float* Wa      = (const float*)d_in[6];
    const float* g0      = (const float*)d_in[7];
    const float* WE      = (const float*)d_in[8];
    const float* WR      = (const float*)d_in[9];

    const int B  = in_sizes[0] / 3;
    const int E  = in_sizes[2];
    const int N  = in_sizes[3] / DDIM;
    const int R  = in_sizes[4] / DDIM;
    const int NS = 2 * B;
    const int* srcIdx = nodes;
    const int* dstIdx = nodes + E;

    // ---- workspace carve (~56 MB) ----
    char* ws = (char*)d_ws;
    size_t off = 0;
    auto carve = [&](size_t bytes) -> void* {
        void* p = ws + off;
        off = (off + bytes + 255) & ~(size_t)255;
        return p;
    };
    float* P        = (float*)carve((size_t)NS * DDIM * 4);
    float* H        = (float*)carve((size_t)NS * DDIM * 4);
    float* ENT      = (float*)carve((size_t)NS * DDIM * 4);
    float* relnew   = (float*)carve((size_t)R * DDIM * 4);
    float* WET      = (float*)carve((size_t)DDIM * DDIM * 4);
    float* WRT      = (float*)carve((size_t)DDIM * DDIM * 4);
    float* invNorm  = (float*)carve((size_t)N * 4);
    float* score_e  = (float*)carve((size_t)MAXM * 4);
    float* score_s  = (float*)carve((size_t)NS * 4);
    float* invDen   = (float*)carve((size_t)NS * 4);
    int*   cnt      = (int*)carve((size_t)N * 4);
    int*   rowSt    = (int*)carve((size_t)(N + 1) * 4);
    int*   cursor   = (int*)carve((size_t)N * 4);
    int*   edgeIds  = (int*)carve((size_t)E * 4);
    int*   slotNode = (int*)carve((size_t)NS * 4);
    int*   deg      = (int*)carve((size_t)NS * 4);
    int*   slotOff  = (int*)carve((size_t)(NS + 1) * 4);
    int*   rowsL    = (int*)carve((size_t)MAXM * 4);
    int*   blockTot = (int*)carve((size_t)1024 * 4);
    int*   blockOff = (int*)carve((size_t)1024 * 4);
    (void)ws_size; (void)n_in; (void)out_size;

    auto scan = [&](const int* in, int* out, int n) {
        int G = (n + 1023) / 1024;
        scan1_kernel<<<G, 1024, 0, stream>>>(in, out, blockTot, n);
        scan2_kernel<<<1, 1024, 0, stream>>>(blockTot, blockOff, out + n, G);
        scan3_kernel<<<G, 1024, 0, stream>>>(out, blockOff, n);
    };

    // 1. CSR over src
    hipMemsetAsync(cnt, 0, (size_t)N * 4, stream);
    hist_kernel<<<(E + 255) / 256, 256, 0, stream>>>(srcIdx, cnt, E);
    scan(cnt, rowSt, N);
    hipMemcpyAsync(cursor, rowSt, (size_t)N * 4, hipMemcpyDeviceToDevice, stream);
    bucket_kernel<<<(E + 255) / 256, 256, 0, stream>>>(srcIdx, cursor, edgeIds, E);

    // 2. slots
    slotnode_kernel<<<(NS + 255) / 256, 256, 0, stream>>>(triples, slotNode, NS);
    deg_kernel<<<(NS + 255) / 256, 256, 0, stream>>>(slotNode, rowSt, deg, NS);
    scan(deg, slotOff, NS);
    fill_rows_kernel<<<(NS + 255) / 256, 256, 0, stream>>>(slotNode, rowSt, edgeIds,
                                                           slotOff, rowsL, NS);
    const int* Mdev = slotOff + NS;

    // 3. invnorm for referenced rows only
    invnorm_sel_kernel<<<4096, 128, 0, stream>>>(entEmb, slotNode, rowsL, dstIdx,
                                                 Mdev, NS, invNorm);

    // 4. transpose WE, WR (so all GEMMs are NT)
    transpose512_kernel<<<256, 256, 0, stream>>>(WE, WET);
    transpose512_kernel<<<256, 256, 0, stream>>>(WR, WRT);

    // 5. score GEMMs
    hipMemsetAsync(score_e, 0, (size_t)MAXM * 4, stream);
    hipMemsetAsync(score_s, 0, (size_t)NS * 4, stream);
    dim3 gEdge(256, DDIM / BN);
    gemm_mfma_k<0, 1, true><<<gEdge, 256, 0, stream>>>(
        entEmb, invNorm, rowsL, srcIdx, dstIdx, edges, relEmb, g0, slotNode,
        nullptr, W1, Wa, score_e, nullptr, nullptr, nullptr, 0, Mdev);
    dim3 gSlot((NS + BM - 1) / BM, DDIM / BN);
    gemm_mfma_k<1, 1, false><<<gSlot, 256, 0, stream>>>(
        entEmb, invNorm, nullptr, nullptr, nullptr, nullptr, relEmb, g0, slotNode,
        nullptr, W1, Wa, score_s, nullptr, nullptr, nullptr, NS, nullptr);

    // 6. P + denominators
    build_p_kernel<<<NS, 128, 0, stream>>>(entEmb, invNorm, relEmb, g0, slotNode,
                                           rowSt, edgeIds, dstIdx, edges, slotOff,
                                           score_e, score_s, P, invDen);

    // 7. H = elu((P @ W1^T) * invDenom)
    gemm_mfma_k<2, 2, false><<<gSlot, 256, 0, stream>>>(
        entEmb, invNorm, nullptr, nullptr, nullptr, nullptr, relEmb, g0, slotNode,
        P, W1, nullptr, nullptr, invDen, nullptr, H, NS, nullptr);

    // 8. ENT = e0[slot] @ WE + H ; l2norm
    gemm_mfma_k<3, 3, false><<<gSlot, 256, 0, stream>>>(
        entEmb, invNorm, nullptr, nullptr, nullptr, nullptr, relEmb, g0, slotNode,
        nullptr, WET, nullptr, nullptr, nullptr, H, ENT, NS, nullptr);
    l2norm_kernel<<<NS, 128, 0, stream>>>(ENT);

    // 9. relnew = rel_emb @ WR
    dim3 gRel((R + BM - 1) / BM, DDIM / BN);
    gemm_mfma_k<2, 0, false><<<gRel, 256, 0, stream>>>(
        entEmb, invNorm, nullptr, nullptr, nullptr, nullptr, relEmb, g0, slotNode,
        relEmb, WRT, nullptr, nullptr, nullptr, nullptr, relnew, R, nullptr);

    // 10. gather
    gather_out_kernel<<<B * 3, 128, 0, stream>>>(triples, ENT, relnew, (float*)d_out);
}